// Round 5
// baseline (170.766 us; speedup 1.0000x reference)
//
#include <hip/hip_runtime.h>

// LaplacianLoss on a fixed 512x512 grid mesh, B=32.
// Lv[b,(i,j)] = v - (1/deg)*sum(nbrs), nbrs = (i,j+-1),(i+-1,j),(i-1,j+1),(i+1,j-1)
// out = mean over (B,V) of |Lv|^2.
//
// R4 lesson: 9 scalar loads/lane-row + fully-unrolled pipeline -> VGPR=128,
// issue/latency bound. R5: 4 cols/lane, 5 aligned float4 loads per row cover
// own+left+right neighbors entirely in-register (no shuffles, no pipeline,
// no halo). 3 stencil rows reloaded per center row (L1 absorbs 3x). Small
// live state -> __launch_bounds__(256,8) for 8 waves/SIMD.

#define GH 512
#define GW 512
#define GV (GH * GW)
#define ROWF (GW * 3)          // 1536 floats per row
#define NBLK 8192              // 32 batches x 256 row-pairs

__global__ __launch_bounds__(256, 8) void lap_partial_kernel(
    const float* __restrict__ verts, float* __restrict__ partials) {
    const int bid   = blockIdx.x;
    const int b     = bid >> 8;           // batch
    const int rg    = bid & 255;          // row-pair within batch
    const int group = threadIdx.x >> 7;   // which row of the pair
    const int g     = threadIdx.x & 127;  // column group: cols 4g..4g+3
    const int ci    = rg * 2 + group;     // center row

    const float* __restrict__ base = verts + (size_t)b * (GV * 3);
    const float* __restrict__ rowO = base + (size_t)ci * ROWF;

    // float offsets of the 5 aligned chunks a[0..19] = floats 12g-4..12g+15
    const int f1 = 12 * g;
    const int f0 = (g == 0) ? 0 : (f1 - 4);          // clamped: garbage masked
    const int f4 = (g == 127) ? (ROWF - 4) : (f1 + 12);

    const float fl = (g > 0)   ? 1.f : 0.f;  // col t=0 has left neighbor
    const float fr = (g < 127) ? 1.f : 0.f;  // col t=3 has right neighbor
    const float ht = (ci > 0)      ? 1.f : 0.f;
    const float hb = (ci < GH - 1) ? 1.f : 0.f;

    // own row: o[1+3t+w]=left, o[4+3t+w]=center, o[7+3t+w]=right (w=0..2)
    float o[20];
    *(float4*)&o[0]  = *(const float4*)(rowO + f0);
    *(float4*)&o[4]  = *(const float4*)(rowO + f1);
    *(float4*)&o[8]  = *(const float4*)(rowO + f1 + 4);
    *(float4*)&o[12] = *(const float4*)(rowO + f1 + 8);
    *(float4*)&o[16] = *(const float4*)(rowO + f4);

    float s[12];
    // M: masked L + masked R from own row
    #pragma unroll
    for (int t = 0; t < 4; ++t) {
        #pragma unroll
        for (int w = 0; w < 3; ++w) {
            float L = o[1 + 3 * t + w];
            float R = o[7 + 3 * t + w];
            if (t == 0) L *= fl;
            if (t == 3) R *= fr;
            s[3 * t + w] = L + R;
        }
    }

    if (ci > 0) {                         // T row: C + masked R
        const float* __restrict__ rowA = rowO - ROWF;
        float a[20];
        *(float4*)&a[0]  = *(const float4*)(rowA + f0);
        *(float4*)&a[4]  = *(const float4*)(rowA + f1);
        *(float4*)&a[8]  = *(const float4*)(rowA + f1 + 4);
        *(float4*)&a[12] = *(const float4*)(rowA + f1 + 8);
        *(float4*)&a[16] = *(const float4*)(rowA + f4);
        #pragma unroll
        for (int t = 0; t < 4; ++t) {
            #pragma unroll
            for (int w = 0; w < 3; ++w) {
                float R = a[7 + 3 * t + w];
                if (t == 3) R *= fr;
                s[3 * t + w] += a[4 + 3 * t + w] + R;
            }
        }
    }

    if (ci < GH - 1) {                    // B row: C + masked L
        const float* __restrict__ rowB = rowO + ROWF;
        float a[20];
        *(float4*)&a[0]  = *(const float4*)(rowB + f0);
        *(float4*)&a[4]  = *(const float4*)(rowB + f1);
        *(float4*)&a[8]  = *(const float4*)(rowB + f1 + 4);
        *(float4*)&a[12] = *(const float4*)(rowB + f1 + 8);
        *(float4*)&a[16] = *(const float4*)(rowB + f4);
        #pragma unroll
        for (int t = 0; t < 4; ++t) {
            #pragma unroll
            for (int w = 0; w < 3; ++w) {
                float L = a[1 + 3 * t + w];
                if (t == 0) L *= fl;
                s[3 * t + w] += a[4 + 3 * t + w] + L;
            }
        }
    }

    // degrees (matches bincount of the unique-edge construction) + finalize
    float local = 0.f;
    #pragma unroll
    for (int t = 0; t < 4; ++t) {
        const float jl = (t == 0) ? fl : 1.f;
        const float jr = (t == 3) ? fr : 1.f;
        const float deg = (ht + hb) + jl * (1.f + hb) + jr * (1.f + ht);
        const float inv = -1.0f / deg;
        #pragma unroll
        for (int w = 0; w < 3; ++w) {
            const float lv = fmaf(inv, s[3 * t + w], o[4 + 3 * t + w]);
            local = fmaf(lv, lv, local);
        }
    }

    // block reduction: wave shuffle -> LDS -> one store per block
    #pragma unroll
    for (int off = 32; off > 0; off >>= 1)
        local += __shfl_down(local, off, 64);

    __shared__ float wsum[4];
    const int lane = threadIdx.x & 63;
    const int wave = threadIdx.x >> 6;
    if (lane == 0) wsum[wave] = local;
    __syncthreads();
    if (threadIdx.x == 0)
        partials[bid] = wsum[0] + wsum[1] + wsum[2] + wsum[3];
}

__global__ __launch_bounds__(256) void lap_final_kernel(
    const float* __restrict__ partials, float* __restrict__ out, int nblk, int B) {
    float local = 0.0f;
    for (int k = threadIdx.x; k < nblk; k += 256)
        local += partials[k];

    #pragma unroll
    for (int off = 32; off > 0; off >>= 1)
        local += __shfl_down(local, off, 64);

    __shared__ float wsum[4];
    const int lane = threadIdx.x & 63;
    const int wid  = threadIdx.x >> 6;
    if (lane == 0) wsum[wid] = local;
    __syncthreads();

    if (threadIdx.x == 0) {
        const float s = wsum[0] + wsum[1] + wsum[2] + wsum[3];
        out[0] = s / ((float)B * (float)GV);
    }
}

extern "C" void kernel_launch(void* const* d_in, const int* in_sizes, int n_in,
                              void* d_out, int out_size, void* d_ws, size_t ws_size,
                              hipStream_t stream) {
    const float* verts = (const float*)d_in[0];
    float* out = (float*)d_out;
    float* partials = (float*)d_ws;                // 8192 floats = 32 KB

    const int B = in_sizes[0] / (GV * 3);          // 32

    lap_partial_kernel<<<NBLK, 256, 0, stream>>>(verts, partials);
    lap_final_kernel<<<1, 256, 0, stream>>>(partials, out, NBLK, B);
}

// Round 6
// 159.347 us; speedup vs baseline: 1.0717x; 1.0717x over previous
//
#include <hip/hip_runtime.h>

// LaplacianLoss on a fixed 512x512 grid mesh, B=32.
// Lv[b,(i,j)] = v - (1/deg)*sum(nbrs), nbrs = (i,j+-1),(i+-1,j),(i-1,j+1),(i+1,j-1)
// out = mean over (B,V) of |Lv|^2.
//
// R5 lesson: all AoS strided register schemes pay ~5x L1 line-touch
// amplification (~40 us). R6: coalesced float4 global->LDS staging (1x line
// touches), 2-slot rolling LDS window, stencil reads hit only the NEW row
// (T/M/C combos carried in registers), one barrier per row. Grid-edge halo
// cols/rows are zeros in LDS so sums need no masks; only deg does.

#define GH 512
#define GW 512
#define GV (GH * GW)
#define RI 16
#define NCHUNK (GH / RI)           // 32
#define ROWF (GW * 3)              // 1536 floats per global row
#define LROW 1544                  // LDS row stride (floats): 1542 data + 2 pad
#define NITER (RI + 2)             // 18
#define NBLK (32 * NCHUNK)         // 1024

__global__ __launch_bounds__(256, 4) void lap_partial_kernel(
    const float* __restrict__ verts, float* __restrict__ partials) {
    __shared__ float lds[2 * LROW];            // 12.3 KB

    const int bid   = blockIdx.x;
    const int batch = bid >> 5;
    const int chunk = bid & (NCHUNK - 1);
    const int i0    = chunk * RI;
    const int t     = threadIdx.x;
    const float* __restrict__ base = verts + (size_t)batch * (GV * 3);

    // zero halo floats (cols -1 and 512 of each slot) once; never rewritten
    if (t < 12) {
        const int slot = t / 6, o = t - 6 * slot;
        lds[slot * LROW + 1536 + o] = 0.0f;
    }

    // thread owns cols 2t (even) and 2t+1 (odd)
    const float jle = (t > 0)   ? 1.f : 0.f;   // even col has left nbr
    const float jro = (t < 255) ? 1.f : 0.f;   // odd col has right nbr
    const int fL = (t == 0)   ? 1536 : (6 * t - 3);   // left col xyz
    const int fE = 6 * t;                              // even col xyz
    const int fO = 6 * t + 3;                          // odd col xyz
    const int fR = (t == 255) ? 1539 : (6 * t + 6);   // right col xyz

    // -1/deg, deg = (ht+hb) + jl*(1+hb) + jr*(1+ht)
    const float invE_m = -1.f / (4.f + 2.f * jle);
    const float invO_m = -1.f / (4.f + 2.f * jro);
    const float invE_t = -1.f / (2.f + 2.f * jle);
    const float invO_t = -1.f / (3.f + jro);
    const float invE_b = -1.f / (3.f + jle);
    const float invO_b = -1.f / (2.f + 2.f * jro);

    // preload row i0-1 (coalesced float4; zeros if out of grid)
    float4 a0, a1;
    {
        const int r = i0 - 1;
        if (r >= 0) {
            const float4* rp = (const float4*)(base + (size_t)r * ROWF);
            a0 = rp[t];
            a1 = (t < 128) ? rp[256 + t] : make_float4(0.f, 0.f, 0.f, 0.f);
        } else {
            a0 = make_float4(0.f, 0.f, 0.f, 0.f); a1 = a0;
        }
    }
    __syncthreads();   // halo zeros visible before first reads

    // carried state: T2=T(c-1), T1=T(c), M1=M(c), C1=C(c)  (6 floats each)
    float T2Ex=0,T2Ey=0,T2Ez=0, T2Ox=0,T2Oy=0,T2Oz=0;
    float T1Ex=0,T1Ey=0,T1Ez=0, T1Ox=0,T1Oy=0,T1Oz=0;
    float M1Ex=0,M1Ey=0,M1Ez=0, M1Ox=0,M1Oy=0,M1Oz=0;
    float C1Ex=0,C1Ey=0,C1Ez=0, C1Ox=0,C1Oy=0,C1Oz=0;
    float local = 0.f;

    for (int k = 0; k < NITER; ++k) {
        float* lp = lds + (k & 1) * LROW;

        // stage row n = i0-1+k from preloaded regs (coalesced b128 writes)
        *(float4*)(lp + 4 * t) = a0;
        if (t < 128) *(float4*)(lp + 1024 + 4 * t) = a1;

        // preload row i0+k for next iter (latency spans barrier+compute)
        if (k < NITER - 1) {
            const int rn = i0 + k;
            if (rn < GH) {
                const float4* rp = (const float4*)(base + (size_t)rn * ROWF);
                a0 = rp[t];
                a1 = (t < 128) ? rp[256 + t] : make_float4(0.f, 0.f, 0.f, 0.f);
            } else {
                a0 = make_float4(0.f, 0.f, 0.f, 0.f); a1 = a0;
            }
        }
        __syncthreads();

        // read new row n: xyz of left / even / odd / right cols
        const float Lx = lp[fL], Ly = lp[fL + 1], Lz = lp[fL + 2];
        const float Ex = lp[fE], Ey = lp[fE + 1], Ez = lp[fE + 2];
        const float Ox = lp[fO], Oy = lp[fO + 1], Oz = lp[fO + 2];
        const float Rx = lp[fR], Ry = lp[fR + 1], Rz = lp[fR + 2];

        // combos for row n:  B = C+L (bottom contrib), T = C+R, M = L+R
        const float BnEx = Ex + Lx, BnEy = Ey + Ly, BnEz = Ez + Lz;
        const float BnOx = Ox + Ex, BnOy = Oy + Ey, BnOz = Oz + Ez;
        const float TnEx = Ex + Ox, TnEy = Ey + Oy, TnEz = Ez + Oz;
        const float TnOx = Ox + Rx, TnOy = Oy + Ry, TnOz = Oz + Rz;
        const float MnEx = Lx + Ox, MnEy = Ly + Oy, MnEz = Lz + Oz;
        const float MnOx = Ex + Rx, MnOy = Ey + Ry, MnOz = Ez + Rz;

        // finalize center c = i0+k-2: sum = T(c-1) + M(c) + B(c+1)
        if (k >= 2) {
            const int c = i0 + k - 2;
            float invE = invE_m, invO = invO_m;
            if (c == 0)            { invE = invE_t; invO = invO_t; }
            else if (c == GH - 1)  { invE = invE_b; invO = invO_b; }

            float s, lv;
            s = T2Ex + M1Ex + BnEx; lv = fmaf(invE, s, C1Ex); local = fmaf(lv, lv, local);
            s = T2Ey + M1Ey + BnEy; lv = fmaf(invE, s, C1Ey); local = fmaf(lv, lv, local);
            s = T2Ez + M1Ez + BnEz; lv = fmaf(invE, s, C1Ez); local = fmaf(lv, lv, local);
            s = T2Ox + M1Ox + BnOx; lv = fmaf(invO, s, C1Ox); local = fmaf(lv, lv, local);
            s = T2Oy + M1Oy + BnOy; lv = fmaf(invO, s, C1Oy); local = fmaf(lv, lv, local);
            s = T2Oz + M1Oz + BnOz; lv = fmaf(invO, s, C1Oz); local = fmaf(lv, lv, local);
        }

        // rotate: T2<-T1, T1<-Tn, M1<-Mn, C1<-Cn
        T2Ex = T1Ex; T2Ey = T1Ey; T2Ez = T1Ez; T2Ox = T1Ox; T2Oy = T1Oy; T2Oz = T1Oz;
        T1Ex = TnEx; T1Ey = TnEy; T1Ez = TnEz; T1Ox = TnOx; T1Oy = TnOy; T1Oz = TnOz;
        M1Ex = MnEx; M1Ey = MnEy; M1Ez = MnEz; M1Ox = MnOx; M1Oy = MnOy; M1Oz = MnOz;
        C1Ex = Ex;   C1Ey = Ey;   C1Ez = Ez;   C1Ox = Ox;   C1Oy = Oy;   C1Oz = Oz;
    }

    // block reduction: wave shuffle -> LDS -> one store per block
    #pragma unroll
    for (int off = 32; off > 0; off >>= 1)
        local += __shfl_down(local, off, 64);

    __shared__ float wsum[4];
    const int lane = t & 63;
    const int wave = t >> 6;
    if (lane == 0) wsum[wave] = local;
    __syncthreads();
    if (t == 0)
        partials[bid] = wsum[0] + wsum[1] + wsum[2] + wsum[3];
}

__global__ __launch_bounds__(256) void lap_final_kernel(
    const float* __restrict__ partials, float* __restrict__ out, int nblk, int B) {
    float local = 0.0f;
    for (int k = threadIdx.x; k < nblk; k += 256)
        local += partials[k];

    #pragma unroll
    for (int off = 32; off > 0; off >>= 1)
        local += __shfl_down(local, off, 64);

    __shared__ float wsum[4];
    const int lane = threadIdx.x & 63;
    const int wid  = threadIdx.x >> 6;
    if (lane == 0) wsum[wid] = local;
    __syncthreads();

    if (threadIdx.x == 0) {
        const float s = wsum[0] + wsum[1] + wsum[2] + wsum[3];
        out[0] = s / ((float)B * (float)GV);
    }
}

extern "C" void kernel_launch(void* const* d_in, const int* in_sizes, int n_in,
                              void* d_out, int out_size, void* d_ws, size_t ws_size,
                              hipStream_t stream) {
    const float* verts = (const float*)d_in[0];
    float* out = (float*)d_out;
    float* partials = (float*)d_ws;            // 1024 floats = 4 KB

    const int B = in_sizes[0] / (GV * 3);      // 32

    lap_partial_kernel<<<NBLK, 256, 0, stream>>>(verts, partials);
    lap_final_kernel<<<1, 256, 0, stream>>>(partials, out, NBLK, B);
}